// Round 1
// baseline (113.304 us; speedup 1.0000x reference)
//
#include <hip/hip_runtime.h>

// RelativePositionalEncoding:
//   out[b,i,j,k] = W[k][clip(index[b,i]-index[b,j]+32, 0, 64)] + bias[k]
//   B=4, N=2048, ATTN_DIM=8, N_REL_POS=65  (derived generically at launch)
//
// 512 MiB float32 output, ~40 KB inputs -> pure HBM-write-bound.
// One block per (b,i) output row; table (W.T + bias, 520 floats) and the
// batch's index row staged in LDS; streaming nontemporal float4 stores.

#define MAX_REL 32
#define NRP 65          // 2*MAX_REL + 1
#define AD 8            // ATTN_DIM

typedef float f4 __attribute__((ext_vector_type(4)));

__global__ __launch_bounds__(256) void relpos_kernel(
    const int* __restrict__ index,
    const float* __restrict__ W,      // [AD][NRP] row-major
    const float* __restrict__ bias,   // [AD]
    float* __restrict__ out,          // [B][N][N][AD]
    int N)
{
    extern __shared__ char smem[];
    float* s_tabf = (float*)smem;                       // [NRP][AD] fused table
    f4*    s_tab4 = (f4*)smem;                          // same, as float4 pairs
    int*   s_idx  = (int*)(smem + NRP * AD * sizeof(float)); // [N] index row

    const int tid = threadIdx.x;
    const int i   = blockIdx.x;   // row within batch
    const int bb  = blockIdx.y;   // batch

    // Build fused table: s_tabf[p*8 + k] = W[k*NRP + p] + bias[k]
    for (int t = tid; t < NRP * AD; t += 256) {
        int p = t >> 3;
        int k = t & 7;
        s_tabf[t] = W[k * NRP + p] + bias[k];
    }
    // Stage this batch's index row
    const int* irow = index + (size_t)bb * (size_t)N;
    for (int t = tid; t < N; t += 256) {
        s_idx[t] = irow[t];
    }
    __syncthreads();

    const int idx_i = s_idx[i];
    const int vecs  = N * 2;  // float4 chunks per output row (N * AD / 4)
    f4* orow = (f4*)(out + ((size_t)bb * (size_t)N + (size_t)i) * (size_t)N * AD);

    for (int f = tid; f < vecs; f += 256) {
        int j = f >> 1;
        int c = idx_i - s_idx[j] + MAX_REL;
        c = c < 0 ? 0 : (c > NRP - 1 ? NRP - 1 : c);
        f4 v = s_tab4[c * 2 + (f & 1)];
        __builtin_nontemporal_store(v, &orow[f]);
    }
}

extern "C" void kernel_launch(void* const* d_in, const int* in_sizes, int n_in,
                              void* d_out, int out_size, void* d_ws, size_t ws_size,
                              hipStream_t stream) {
    const int*   index = (const int*)d_in[0];
    const float* W     = (const float*)d_in[1];
    const float* bias  = (const float*)d_in[2];
    float*       out   = (float*)d_out;

    const long long BN = in_sizes[0];                       // B * N
    const long long N  = (long long)out_size / (BN * AD);   // out = B*N*N*AD
    const long long B  = BN / N;

    const size_t smem = NRP * AD * sizeof(float) + (size_t)N * sizeof(int);
    dim3 grid((unsigned)N, (unsigned)B, 1);
    relpos_kernel<<<grid, 256, smem, stream>>>(index, W, bias, out, (int)N);
}

// Round 2
// 106.917 us; speedup vs baseline: 1.0597x; 1.0597x over previous
//
#include <hip/hip_runtime.h>

// RelativePositionalEncoding:
//   out[b,i,j,k] = W[k][clip(index[b,i]-index[b,j]+32, 0, 64)] + bias[k]
//   B=4, N=2048, ATTN_DIM=8, N_REL_POS=65
//
// 512 MiB fp32 output, ~40 KB inputs -> pure HBM-write-bound.
// ROWS rows per block: stage table + index row once, register-cache the
// per-thread index values (j-partition identical across rows), then per row
// emit a fully-unrolled burst of 16 nontemporal float4 stores.

#define MAX_REL 32
#define NRP 65          // 2*MAX_REL + 1
#define AD 8            // ATTN_DIM
#define ROWS 8
#define BLK 256
#define SLOTS 16        // fast path: N*2/BLK == 16  (N == 2048)

typedef float f4 __attribute__((ext_vector_type(4)));

__global__ __launch_bounds__(BLK) void relpos_kernel(
    const int* __restrict__ index,
    const float* __restrict__ W,      // [AD][NRP]
    const float* __restrict__ bias,   // [AD]
    float* __restrict__ out,          // [B][N][N][AD]
    int N)
{
    extern __shared__ char smem[];
    float* s_tabf = (float*)smem;                            // [NRP][AD] fused W.T + b
    f4*    s_tab4 = (f4*)smem;
    int*   s_idx  = (int*)(smem + NRP * AD * sizeof(float)); // [N]

    const int tid = threadIdx.x;
    const int i0  = blockIdx.x * ROWS;
    const int bb  = blockIdx.y;

    for (int t = tid; t < NRP * AD; t += BLK) {
        int p = t >> 3;
        int k = t & 7;
        s_tabf[t] = W[k * NRP + p] + bias[k];
    }
    const int* irow = index + (size_t)bb * (size_t)N;
    for (int t = tid; t < N; t += BLK) {
        s_idx[t] = irow[t];
    }
    __syncthreads();

    const int vecs = N * 2;  // float4 chunks per output row
    f4* obase = (f4*)out + ((size_t)bb * (size_t)N + (size_t)i0) * (size_t)(N * 2);

    if (vecs == SLOTS * BLK) {
        // Fast path: register-cache this thread's SLOTS index values once.
        int sj[SLOTS];
        #pragma unroll
        for (int k = 0; k < SLOTS; ++k)
            sj[k] = s_idx[(tid + k * BLK) >> 1];

        #pragma unroll
        for (int r = 0; r < ROWS; ++r) {
            const int i = i0 + r;
            if (i >= N) break;
            const int idx_i = s_idx[i] + MAX_REL;
            f4* orow = obase + (size_t)r * (size_t)vecs;
            #pragma unroll
            for (int k = 0; k < SLOTS; ++k) {
                const int f = tid + k * BLK;
                int c = idx_i - sj[k];
                c = c < 0 ? 0 : (c > NRP - 1 ? NRP - 1 : c);
                f4 v = s_tab4[c * 2 + (f & 1)];
                __builtin_nontemporal_store(v, &orow[f]);
            }
        }
    } else {
        // Generic path.
        for (int r = 0; r < ROWS; ++r) {
            const int i = i0 + r;
            if (i >= N) break;
            const int idx_i = s_idx[i] + MAX_REL;
            f4* orow = obase + (size_t)r * (size_t)vecs;
            for (int f = tid; f < vecs; f += BLK) {
                int c = idx_i - s_idx[f >> 1];
                c = c < 0 ? 0 : (c > NRP - 1 ? NRP - 1 : c);
                f4 v = s_tab4[c * 2 + (f & 1)];
                __builtin_nontemporal_store(v, &orow[f]);
            }
        }
    }
}

extern "C" void kernel_launch(void* const* d_in, const int* in_sizes, int n_in,
                              void* d_out, int out_size, void* d_ws, size_t ws_size,
                              hipStream_t stream) {
    const int*   index = (const int*)d_in[0];
    const float* W     = (const float*)d_in[1];
    const float* bias  = (const float*)d_in[2];
    float*       out   = (float*)d_out;

    const long long BN = in_sizes[0];                       // B * N
    const long long N  = (long long)out_size / (BN * AD);   // out = B*N*N*AD
    const long long B  = BN / N;

    const size_t smem = NRP * AD * sizeof(float) + (size_t)N * sizeof(int);
    dim3 grid((unsigned)((N + ROWS - 1) / ROWS), (unsigned)B, 1);
    relpos_kernel<<<grid, BLK, smem, stream>>>(index, W, bias, out, (int)N);
}

// Round 3
// 103.419 us; speedup vs baseline: 1.0956x; 1.0338x over previous
//
#include <hip/hip_runtime.h>

// RelativePositionalEncoding:
//   out[b,i,j,k] = W[k][clip(index[b,i]-index[b,j]+32, 0, 64)] + bias[k]
//   B=4, N=2048, ATTN_DIM=8, N_REL_POS=65
//
// 512 MiB fp32 output, ~40 KB inputs -> pure HBM-write-bound.
// Round 3 A/B: plain cached stores instead of nontemporal (fillBuffer hits
// 85% peak with plain stores; we capped at 63% with nt). Everything else
// identical to round 2.

#define MAX_REL 32
#define NRP 65          // 2*MAX_REL + 1
#define AD 8            // ATTN_DIM
#define ROWS 8
#define BLK 256
#define SLOTS 16        // fast path: N*2/BLK == 16  (N == 2048)

typedef float f4 __attribute__((ext_vector_type(4)));

__global__ __launch_bounds__(BLK) void relpos_kernel(
    const int* __restrict__ index,
    const float* __restrict__ W,      // [AD][NRP]
    const float* __restrict__ bias,   // [AD]
    float* __restrict__ out,          // [B][N][N][AD]
    int N)
{
    extern __shared__ char smem[];
    float* s_tabf = (float*)smem;                            // [NRP][AD] fused W.T + b
    f4*    s_tab4 = (f4*)smem;
    int*   s_idx  = (int*)(smem + NRP * AD * sizeof(float)); // [N]

    const int tid = threadIdx.x;
    const int i0  = blockIdx.x * ROWS;
    const int bb  = blockIdx.y;

    for (int t = tid; t < NRP * AD; t += BLK) {
        int p = t >> 3;
        int k = t & 7;
        s_tabf[t] = W[k * NRP + p] + bias[k];
    }
    const int* irow = index + (size_t)bb * (size_t)N;
    for (int t = tid; t < N; t += BLK) {
        s_idx[t] = irow[t];
    }
    __syncthreads();

    const int vecs = N * 2;  // float4 chunks per output row
    f4* obase = (f4*)out + ((size_t)bb * (size_t)N + (size_t)i0) * (size_t)(N * 2);

    if (vecs == SLOTS * BLK) {
        // Fast path: register-cache this thread's SLOTS index values once.
        int sj[SLOTS];
        #pragma unroll
        for (int k = 0; k < SLOTS; ++k)
            sj[k] = s_idx[(tid + k * BLK) >> 1];

        #pragma unroll
        for (int r = 0; r < ROWS; ++r) {
            const int i = i0 + r;
            if (i >= N) break;
            const int idx_i = s_idx[i] + MAX_REL;
            f4* orow = obase + (size_t)r * (size_t)vecs;
            #pragma unroll
            for (int k = 0; k < SLOTS; ++k) {
                const int f = tid + k * BLK;
                int c = idx_i - sj[k];
                c = c < 0 ? 0 : (c > NRP - 1 ? NRP - 1 : c);
                f4 v = s_tab4[c * 2 + (f & 1)];
                orow[f] = v;
            }
        }
    } else {
        // Generic path.
        for (int r = 0; r < ROWS; ++r) {
            const int i = i0 + r;
            if (i >= N) break;
            const int idx_i = s_idx[i] + MAX_REL;
            f4* orow = obase + (size_t)r * (size_t)vecs;
            for (int f = tid; f < vecs; f += BLK) {
                int c = idx_i - s_idx[f >> 1];
                c = c < 0 ? 0 : (c > NRP - 1 ? NRP - 1 : c);
                f4 v = s_tab4[c * 2 + (f & 1)];
                orow[f] = v;
            }
        }
    }
}

extern "C" void kernel_launch(void* const* d_in, const int* in_sizes, int n_in,
                              void* d_out, int out_size, void* d_ws, size_t ws_size,
                              hipStream_t stream) {
    const int*   index = (const int*)d_in[0];
    const float* W     = (const float*)d_in[1];
    const float* bias  = (const float*)d_in[2];
    float*       out   = (float*)d_out;

    const long long BN = in_sizes[0];                       // B * N
    const long long N  = (long long)out_size / (BN * AD);   // out = B*N*N*AD
    const long long B  = BN / N;

    const size_t smem = NRP * AD * sizeof(float) + (size_t)N * sizeof(int);
    dim3 grid((unsigned)((N + ROWS - 1) / ROWS), (unsigned)B, 1);
    relpos_kernel<<<grid, BLK, smem, stream>>>(index, W, bias, out, (int)N);
}

// Round 4
// 99.358 us; speedup vs baseline: 1.1404x; 1.0409x over previous
//
#include <hip/hip_runtime.h>

// RelativePositionalEncoding:
//   out[b,i,j,k] = W[k][clip(index[b,i]-index[b,j]+32, 0, 64)] + bias[k]
//   B=4, N=2048, ATTN_DIM=8, N_REL_POS=65
//
// 512 MiB fp32 output, ~40 KB inputs -> pure HBM-write-bound.
// Round 4: ROWS 8 -> 4 (2048 blocks, 8 blocks/CU = 32 waves/CU, full
// occupancy) to deepen the outstanding-store pool. launch_bounds(256,8)
// caps VGPRs at 64 so occupancy isn't register-clipped.

#define MAX_REL 32
#define NRP 65          // 2*MAX_REL + 1
#define AD 8            // ATTN_DIM
#define ROWS 4
#define BLK 256
#define SLOTS 16        // fast path: N*2/BLK == 16  (N == 2048)

typedef float f4 __attribute__((ext_vector_type(4)));

__global__ __launch_bounds__(BLK, 8) void relpos_kernel(
    const int* __restrict__ index,
    const float* __restrict__ W,      // [AD][NRP]
    const float* __restrict__ bias,   // [AD]
    float* __restrict__ out,          // [B][N][N][AD]
    int N)
{
    extern __shared__ char smem[];
    float* s_tabf = (float*)smem;                            // [NRP][AD] fused W.T + b
    f4*    s_tab4 = (f4*)smem;
    int*   s_idx  = (int*)(smem + NRP * AD * sizeof(float)); // [N]

    const int tid = threadIdx.x;
    const int i0  = blockIdx.x * ROWS;
    const int bb  = blockIdx.y;

    for (int t = tid; t < NRP * AD; t += BLK) {
        int p = t >> 3;
        int k = t & 7;
        s_tabf[t] = W[k * NRP + p] + bias[k];
    }
    const int* irow = index + (size_t)bb * (size_t)N;
    for (int t = tid; t < N; t += BLK) {
        s_idx[t] = irow[t];
    }
    __syncthreads();

    const int vecs = N * 2;  // float4 chunks per output row
    f4* obase = (f4*)out + ((size_t)bb * (size_t)N + (size_t)i0) * (size_t)(N * 2);

    if (vecs == SLOTS * BLK) {
        // Fast path: register-cache this thread's SLOTS index values once.
        int sj[SLOTS];
        #pragma unroll
        for (int k = 0; k < SLOTS; ++k)
            sj[k] = s_idx[(tid + k * BLK) >> 1];

        #pragma unroll
        for (int r = 0; r < ROWS; ++r) {
            const int i = i0 + r;
            if (i >= N) break;
            const int idx_i = s_idx[i] + MAX_REL;
            f4* orow = obase + (size_t)r * (size_t)vecs;
            #pragma unroll
            for (int k = 0; k < SLOTS; ++k) {
                const int f = tid + k * BLK;
                int c = idx_i - sj[k];
                c = c < 0 ? 0 : (c > NRP - 1 ? NRP - 1 : c);
                f4 v = s_tab4[c * 2 + (f & 1)];
                orow[f] = v;
            }
        }
    } else {
        // Generic path.
        for (int r = 0; r < ROWS; ++r) {
            const int i = i0 + r;
            if (i >= N) break;
            const int idx_i = s_idx[i] + MAX_REL;
            f4* orow = obase + (size_t)r * (size_t)vecs;
            for (int f = tid; f < vecs; f += BLK) {
                int c = idx_i - s_idx[f >> 1];
                c = c < 0 ? 0 : (c > NRP - 1 ? NRP - 1 : c);
                f4 v = s_tab4[c * 2 + (f & 1)];
                orow[f] = v;
            }
        }
    }
}

extern "C" void kernel_launch(void* const* d_in, const int* in_sizes, int n_in,
                              void* d_out, int out_size, void* d_ws, size_t ws_size,
                              hipStream_t stream) {
    const int*   index = (const int*)d_in[0];
    const float* W     = (const float*)d_in[1];
    const float* bias  = (const float*)d_in[2];
    float*       out   = (float*)d_out;

    const long long BN = in_sizes[0];                       // B * N
    const long long N  = (long long)out_size / (BN * AD);   // out = B*N*N*AD
    const long long B  = BN / N;

    const size_t smem = NRP * AD * sizeof(float) + (size_t)N * sizeof(int);
    dim3 grid((unsigned)((N + ROWS - 1) / ROWS), (unsigned)B, 1);
    relpos_kernel<<<grid, BLK, smem, stream>>>(index, W, bias, out, (int)N);
}

// Round 5
// 97.509 us; speedup vs baseline: 1.1620x; 1.0190x over previous
//
#include <hip/hip_runtime.h>

// RelativePositionalEncoding:
//   out[b,i,j,k] = W[k][clip(index[b,i]-index[b,j]+32, 0, 64)] + bias[k]
//   B=4, N=2048, ATTN_DIM=8, N_REL_POS=65
//
// 512 MiB fp32 output, ~40 KB inputs -> pure HBM-write-bound.
// Round 5: per-wave CONTIGUOUS store partition. f = wave*1024 + k*64 + lane
// makes each wave's 16 stores a sequential 16 KB run (+1 KB per k), so the
// compiler folds addresses into offset: immediates and the L2 sees ascending
// full-line streams per wave. Grid 2048 blocks = 8 blocks/CU, all resident.

#define MAX_REL 32
#define NRP 65          // 2*MAX_REL + 1
#define AD 8            // ATTN_DIM
#define ROWS 4
#define BLK 256
#define SLOTS 16        // fast path: N*2/BLK == 16  (N == 2048)

typedef float f4 __attribute__((ext_vector_type(4)));

__global__ __launch_bounds__(BLK, 8) void relpos_kernel(
    const int* __restrict__ index,
    const float* __restrict__ W,      // [AD][NRP]
    const float* __restrict__ bias,   // [AD]
    float* __restrict__ out,          // [B][N][N][AD]
    int N)
{
    extern __shared__ char smem[];
    float* s_tabf = (float*)smem;                            // [NRP][AD] fused W.T + b
    f4*    s_tab4 = (f4*)smem;
    int*   s_idx  = (int*)(smem + NRP * AD * sizeof(float)); // [N]

    const int tid = threadIdx.x;
    const int i0  = blockIdx.x * ROWS;
    const int bb  = blockIdx.y;

    for (int t = tid; t < NRP * AD; t += BLK) {
        int p = t >> 3;
        int k = t & 7;
        s_tabf[t] = W[k * NRP + p] + bias[k];
    }
    const int* irow = index + (size_t)bb * (size_t)N;
    for (int t = tid; t < N; t += BLK) {
        s_idx[t] = irow[t];
    }
    __syncthreads();

    const int vecs = N * 2;  // float4 chunks per output row
    f4* obase = (f4*)out + ((size_t)bb * (size_t)N + (size_t)i0) * (size_t)(N * 2);

    if (vecs == SLOTS * BLK) {
        const int wave = tid >> 6;
        const int lane = tid & 63;
        const int par  = lane & 1;       // which half of the f4-pair
        const int jrow = (lane >> 1);    // 0..31

        // Register-cache this thread's SLOTS index values once (same j
        // partition for every row). sj[k] covers j = wave*512 + k*32 + jrow.
        int sj[SLOTS];
        #pragma unroll
        for (int k = 0; k < SLOTS; ++k)
            sj[k] = s_idx[wave * 512 + k * 32 + jrow];

        #pragma unroll
        for (int r = 0; r < ROWS; ++r) {
            const int i = i0 + r;
            if (i >= N) break;
            const int idx_i = s_idx[i] + MAX_REL;
            // wave's contiguous 16 KB run within this 64 KB row
            f4* wbase = obase + (size_t)r * (size_t)vecs + wave * 1024 + lane;
            #pragma unroll
            for (int k = 0; k < SLOTS; ++k) {
                int c = idx_i - sj[k];
                c = c < 0 ? 0 : (c > NRP - 1 ? NRP - 1 : c);
                f4 v = s_tab4[c * 2 + par];
                wbase[k * 64] = v;       // +1 KB per k -> offset immediates
            }
        }
    } else {
        // Generic path.
        for (int r = 0; r < ROWS; ++r) {
            const int i = i0 + r;
            if (i >= N) break;
            const int idx_i = s_idx[i] + MAX_REL;
            f4* orow = obase + (size_t)r * (size_t)vecs;
            for (int f = tid; f < vecs; f += BLK) {
                int c = idx_i - s_idx[f >> 1];
                c = c < 0 ? 0 : (c > NRP - 1 ? NRP - 1 : c);
                f4 v = s_tab4[c * 2 + (f & 1)];
                orow[f] = v;
            }
        }
    }
}

extern "C" void kernel_launch(void* const* d_in, const int* in_sizes, int n_in,
                              void* d_out, int out_size, void* d_ws, size_t ws_size,
                              hipStream_t stream) {
    const int*   index = (const int*)d_in[0];
    const float* W     = (const float*)d_in[1];
    const float* bias  = (const float*)d_in[2];
    float*       out   = (float*)d_out;

    const long long BN = in_sizes[0];                       // B * N
    const long long N  = (long long)out_size / (BN * AD);   // out = B*N*N*AD
    const long long B  = BN / N;

    const size_t smem = NRP * AD * sizeof(float) + (size_t)N * sizeof(int);
    dim3 grid((unsigned)((N + ROWS - 1) / ROWS), (unsigned)B, 1);
    relpos_kernel<<<grid, BLK, smem, stream>>>(index, W, bias, out, (int)N);
}

// Round 6
// 96.406 us; speedup vs baseline: 1.1753x; 1.0114x over previous
//
#include <hip/hip_runtime.h>

// RelativePositionalEncoding:
//   out[b,i,j,k] = W[k][clip(index[b,i]-index[b,j]+32, 0, 64)] + bias[k]
//   B=4, N=2048, ATTN_DIM=8, N_REL_POS=65
//
// 512 MiB fp32 output, ~40 KB inputs -> pure HBM-write-bound.
// Round 6: (a) remove the r-loop break in the fast path (gate on N%ROWS==0)
// so all 4 rows fully unroll -> 64 independent in-flight stores per wave;
// (b) drop the index-row LDS staging: sj[k] loaded directly from global
// (coalesced 128B per instr), idx_i via uniform scalar load. Only the
// 520-float fused table goes through LDS now. Store pattern unchanged
// (per-wave contiguous 16 KB runs, plain cached stores).

#define MAX_REL 32
#define NRP 65          // 2*MAX_REL + 1
#define AD 8            // ATTN_DIM
#define ROWS 4
#define BLK 256
#define SLOTS 16        // fast path: N*2/BLK == 16  (N == 2048)

typedef float f4 __attribute__((ext_vector_type(4)));

__global__ __launch_bounds__(BLK, 8) void relpos_kernel(
    const int* __restrict__ index,
    const float* __restrict__ W,      // [AD][NRP]
    const float* __restrict__ bias,   // [AD]
    float* __restrict__ out,          // [B][N][N][AD]
    int N)
{
    extern __shared__ char smem[];
    float* s_tabf = (float*)smem;                            // [NRP][AD] fused W.T + b
    f4*    s_tab4 = (f4*)smem;
    int*   s_idx  = (int*)(smem + NRP * AD * sizeof(float)); // [N] (generic path only)

    const int tid = threadIdx.x;
    const int i0  = blockIdx.x * ROWS;
    const int bb  = blockIdx.y;
    const int* irow = index + (size_t)bb * (size_t)N;

    for (int t = tid; t < NRP * AD; t += BLK) {
        int p = t >> 3;
        int k = t & 7;
        s_tabf[t] = W[k * NRP + p] + bias[k];
    }

    const int vecs = N * 2;  // float4 chunks per output row
    f4* obase = (f4*)out + ((size_t)bb * (size_t)N + (size_t)i0) * (size_t)(N * 2);

    if (vecs == SLOTS * BLK && (N % ROWS) == 0) {
        // ---- fast path (N == 2048): no index staging, no row-loop break ----
        const int wave = tid >> 6;
        const int lane = tid & 63;
        const int par  = lane & 1;       // which half of the f4-pair
        const int jrow = (lane >> 1);    // 0..31

        // Direct global loads of this thread's SLOTS index values.
        // Per instruction: 64 lanes read 32 consecutive ints (2-way dup) = 128B.
        int sj[SLOTS];
        #pragma unroll
        for (int k = 0; k < SLOTS; ++k)
            sj[k] = irow[wave * 512 + k * 32 + jrow];

        // Uniform scalar loads of the row indices.
        int idx_i[ROWS];
        #pragma unroll
        for (int r = 0; r < ROWS; ++r)
            idx_i[r] = irow[i0 + r] + MAX_REL;

        __syncthreads();   // table ready

        #pragma unroll
        for (int r = 0; r < ROWS; ++r) {
            // wave's contiguous 16 KB run within this 64 KB row
            f4* wbase = obase + (size_t)r * (size_t)vecs + wave * 1024 + lane;
            #pragma unroll
            for (int k = 0; k < SLOTS; ++k) {
                int c = idx_i[r] - sj[k];
                c = c < 0 ? 0 : (c > NRP - 1 ? NRP - 1 : c);
                f4 v = s_tab4[c * 2 + par];
                wbase[k * 64] = v;       // +1 KB per k -> offset immediates
            }
        }
    } else {
        // ---- generic path: LDS-staged index row ----
        for (int t = tid; t < N; t += BLK)
            s_idx[t] = irow[t];
        __syncthreads();

        for (int r = 0; r < ROWS; ++r) {
            const int i = i0 + r;
            if (i >= N) break;
            const int ii = s_idx[i] + MAX_REL;
            f4* orow = obase + (size_t)r * (size_t)vecs;
            for (int f = tid; f < vecs; f += BLK) {
                int c = ii - s_idx[f >> 1];
                c = c < 0 ? 0 : (c > NRP - 1 ? NRP - 1 : c);
                f4 v = s_tab4[c * 2 + (f & 1)];
                orow[f] = v;
            }
        }
    }
}

extern "C" void kernel_launch(void* const* d_in, const int* in_sizes, int n_in,
                              void* d_out, int out_size, void* d_ws, size_t ws_size,
                              hipStream_t stream) {
    const int*   index = (const int*)d_in[0];
    const float* W     = (const float*)d_in[1];
    const float* bias  = (const float*)d_in[2];
    float*       out   = (float*)d_out;

    const long long BN = in_sizes[0];                       // B * N
    const long long N  = (long long)out_size / (BN * AD);   // out = B*N*N*AD
    const long long B  = BN / N;

    const size_t smem = NRP * AD * sizeof(float) + (size_t)N * sizeof(int);
    dim3 grid((unsigned)((N + ROWS - 1) / ROWS), (unsigned)B, 1);
    relpos_kernel<<<grid, BLK, smem, stream>>>(index, W, bias, out, (int)N);
}